// Round 9
// baseline (803.483 us; speedup 1.0000x reference)
//
#include <hip/hip_runtime.h>
#include <hip/hip_fp16.h>

#define NM 100000
#define NNZE 1600000
#define C 128
#define NBKT 391          // coarse buckets (256 rows each)
#define NPB 391           // blocks of 4096 entries
#define GEMMB 512
#define VB 128
#define SPMMB (NM / 4)

typedef unsigned long long u64;
typedef __attribute__((ext_vector_type(8))) short bf16x8;
typedef __attribute__((ext_vector_type(4))) float f32x4;

__device__ __forceinline__ float sigmoidf_(float x) {
    return 1.0f / (1.0f + __expf(-x));
}
__device__ __forceinline__ short f2bf(float f) {          // fp32 -> bf16 RNE
    unsigned u = __float_as_uint(f);
    return (short)((u + 0x7FFFu + ((u >> 16) & 1u)) >> 16);
}
__device__ __forceinline__ float bf2f(short s) {
    return __uint_as_float(((unsigned)(unsigned short)s) << 16);
}

// ---------------- role bodies ----------------

// Y(fp16) = X @ W via split-bf16 MFMA (xh*Wh + xh*Wl + xl*Wh)
__device__ void gemm_body(int gb, const float* __restrict__ X,
                          const float* __restrict__ W, __half* __restrict__ Y) {
    __shared__ short Whi[16384];   // 32 KB
    __shared__ short Wlo[16384];   // 32 KB
    int t = threadIdx.x;
    for (int e = t; e < 16384; e += 256) {
        int k = e >> 7, c = e & 127;
        float w = W[e];
        short hi = f2bf(w);
        short lo = f2bf(w - bf2f(hi));
        int kt = k >> 5, kin = k & 31, ct = c >> 4, cin = c & 15;
        int lane = ((kin >> 3) << 4) | cin;
        int idx = (((kt << 3) | ct) << 9) + (lane << 3) + (kin & 7);
        Whi[idx] = hi;
        Wlo[idx] = lo;
    }
    __syncthreads();
    int lane = t & 63;
    int wv = t >> 6;
    int gw = gb * 4 + wv;
    const int wstride = GEMMB * 4;
    int r_lane = lane & 15;
    int kg = lane >> 4;
    const int NT = NM / 16;
    for (int tile = gw; tile < NT; tile += wstride) {
        int row = tile * 16 + r_lane;
        bf16x8 ahi[4], alo[4];
#pragma unroll
        for (int kt = 0; kt < 4; ++kt) {
            const float4* xp = (const float4*)&X[(long)row * C + kt * 32 + kg * 8];
            float4 v0 = xp[0];
            float4 v1 = xp[1];
            float vv[8] = {v0.x, v0.y, v0.z, v0.w, v1.x, v1.y, v1.z, v1.w};
#pragma unroll
            for (int q = 0; q < 8; ++q) {
                short h = f2bf(vv[q]);
                ahi[kt][q] = h;
                alo[kt][q] = f2bf(vv[q] - bf2f(h));
            }
        }
        int rbase = tile * 16 + kg * 4;
#pragma unroll
        for (int ct = 0; ct < 8; ++ct) {
            f32x4 acc = {0.f, 0.f, 0.f, 0.f};
#pragma unroll
            for (int kt = 0; kt < 4; ++kt) {
                int bidx = (((kt << 3) | ct) << 9) + (lane << 3);
                bf16x8 bhi = *(bf16x8*)&Whi[bidx];
                bf16x8 blo = *(bf16x8*)&Wlo[bidx];
                acc = __builtin_amdgcn_mfma_f32_16x16x32_bf16(ahi[kt], bhi, acc, 0, 0, 0);
                acc = __builtin_amdgcn_mfma_f32_16x16x32_bf16(ahi[kt], blo, acc, 0, 0, 0);
                acc = __builtin_amdgcn_mfma_f32_16x16x32_bf16(alo[kt], bhi, acc, 0, 0, 0);
            }
            int ccol = ct * 16 + r_lane;
#pragma unroll
            for (int r = 0; r < 4; ++r)
                Y[(long)(rbase + r) * C + ccol] = __float2half(acc[r]);
        }
    }
}

// rows-only coarse bucket histogram (LDS-aggregated)
__device__ void hist_body(int hb, const int* __restrict__ rows,
                          int* __restrict__ gcnt) {
    __shared__ int hcnt[NBKT];
    int t = threadIdx.x;
    for (int j = t; j < NBKT; j += 256) hcnt[j] = 0;
    __syncthreads();
    long base = (long)hb * 4096;
#pragma unroll
    for (int i = 0; i < 16; ++i) {
        long e = base + i * 256 + t;
        if (e < NNZE) atomicAdd(&hcnt[rows[e] >> 8], 1);
    }
    __syncthreads();
    for (int j = t; j < NBKT; j += 256)
        if (hcnt[j]) atomicAdd(&gcnt[j], hcnt[j]);
}

// scatter into coarse buckets (1 global atomic per block-bucket run) + deg scatter
__device__ void place_body(int pb, const int* __restrict__ rows,
                           const int* __restrict__ cols,
                           const float* __restrict__ vals,
                           int* __restrict__ gCursor, u64* __restrict__ bkt,
                           float* __restrict__ deg) {
    __shared__ int lcnt[NBKT];
    __shared__ int lbase[NBKT];
    int t = threadIdx.x;
    for (int j = t; j < NBKT; j += 256) lcnt[j] = 0;
    __syncthreads();
    long base = (long)pb * 4096;
    int myrow[16];
#pragma unroll
    for (int i = 0; i < 16; ++i) {
        long e = base + i * 256 + t;
        myrow[i] = (e < NNZE) ? rows[e] : -1;
        if (myrow[i] >= 0) atomicAdd(&lcnt[myrow[i] >> 8], 1);
    }
    __syncthreads();
    for (int j = t; j < NBKT; j += 256) {
        int cc = lcnt[j];
        lbase[j] = cc ? atomicAdd(&gCursor[j], cc) : 0;
    }
    __syncthreads();
    for (int j = t; j < NBKT; j += 256) lcnt[j] = 0;
    __syncthreads();
#pragma unroll
    for (int i = 0; i < 16; ++i) {
        long e = base + i * 256 + t;
        if (myrow[i] >= 0) {
            int col = cols[e];
            float v = vals[e];
            unsafeAtomicAdd(&deg[col], v);
            int b = myrow[i] >> 8;
            int p = lbase[b] + atomicAdd(&lcnt[b], 1);
            unsigned meta = ((unsigned)(myrow[i] & 255) << 17) | (unsigned)col;
            bkt[p] = (u64)meta | ((u64)__float_as_uint(v) << 32);
        }
    }
}

// one block per bucket: LDS row-count + block scan -> off[] (plain stores),
// then scatter (col,val) into final CSR order
__device__ void fine_body(int fb, const int* __restrict__ bktBase,
                          const u64* __restrict__ bkt, u64* __restrict__ srt,
                          int* __restrict__ off) {
    __shared__ int fcnt[256];
    __shared__ int fexcl[256];
    __shared__ int fwt[4];
    __shared__ int fwb[4];
    int t = threadIdx.x;
    int base = bktBase[fb];
    int n = bktBase[fb + 1] - base;
    fcnt[t] = 0;
    __syncthreads();
    for (int i = t; i < n; i += 256) {
        unsigned meta = (unsigned)(bkt[base + i] & 0xffffffffu);
        atomicAdd(&fcnt[meta >> 17], 1);
    }
    __syncthreads();
    int lane = t & 63;
    int wid = t >> 6;
    int v = fcnt[t];
    int incl = v;
#pragma unroll
    for (int d = 1; d < 64; d <<= 1) {
        int nn = __shfl_up(incl, d);
        if (lane >= d) incl += nn;
    }
    if (lane == 63) fwt[wid] = incl;
    __syncthreads();
    if (t == 0) {
        int r = 0;
#pragma unroll
        for (int i = 0; i < 4; ++i) { fwb[i] = r; r += fwt[i]; }
    }
    __syncthreads();
    int ex = fwb[wid] + incl - v;
    fexcl[t] = ex;
    int row = fb * 256 + t;
    if (row < NM) off[row] = base + ex;
    fcnt[t] = 0;             // reuse as cursor
    __syncthreads();
    for (int i = t; i < n; i += 256) {
        u64 rec = bkt[base + i];
        unsigned meta = (unsigned)(rec & 0xffffffffu);
        int lr = (int)(meta >> 17);
        unsigned col = meta & 0x1ffffu;
        int p = fexcl[lr] + atomicAdd(&fcnt[lr], 1);
        srt[base + p] = (u64)col | (rec & 0xffffffff00000000ull);
    }
}

// v[k] = sum_m deg[m] * X[m][k]  (exact fp32)
__device__ void v_body(int vb, const float* __restrict__ X,
                       const float* __restrict__ deg, float* __restrict__ v) {
    __shared__ float vsh[256];
    int t = threadIdx.x;
    int k = t & 127;
    int half = t >> 7;
    int m0 = vb * 782;
    int m1 = min(m0 + 782, NM);
    float acc = 0.f;
    for (int m = m0 + half; m < m1; m += 2) acc += deg[m] * X[(long)m * C + k];
    vsh[t] = acc;
    __syncthreads();
    if (t < 128) atomicAdd(&v[k], vsh[t] + vsh[t + 128]);
}

// gather-accumulate one CSR row's channel pair (fp16 xm, fp32 acc, unroll-8)
__device__ float2 spmm_row(int m, const int* __restrict__ off,
                           const u64* __restrict__ srt,
                           const __half* __restrict__ xmh, int c) {
    int s = off[m], e = off[m + 1];
    float2 acc[8];
#pragma unroll
    for (int j = 0; j < 8; ++j) acc[j] = make_float2(0.f, 0.f);
    int i = s;
    for (; i + 7 < e; i += 8) {
        u64 p[8];
#pragma unroll
        for (int j = 0; j < 8; ++j) p[j] = srt[i + j];
        float2 xf[8];
#pragma unroll
        for (int j = 0; j < 8; ++j) {
            int cj = (int)(p[j] & 0xffffffffu);
            __half2 hx = *(const __half2*)&xmh[(long)cj * C + c];
            xf[j] = __half22float2(hx);
        }
#pragma unroll
        for (int j = 0; j < 8; ++j) {
            float v = __uint_as_float((unsigned)(p[j] >> 32));
            acc[j].x += v * xf[j].x;
            acc[j].y += v * xf[j].y;
        }
    }
    for (; i < e; ++i) {
        u64 p0 = srt[i];
        int c0 = (int)(p0 & 0xffffffffu);
        float v0 = __uint_as_float((unsigned)(p0 >> 32));
        __half2 hx = *(const __half2*)&xmh[(long)c0 * C + c];
        float2 xf = __half22float2(hx);
        acc[0].x += v0 * xf.x;
        acc[0].y += v0 * xf.y;
    }
#pragma unroll
    for (int j = 1; j < 8; ++j) {
        acc[0].x += acc[j].x;
        acc[0].y += acc[j].y;
    }
    return acc[0];
}

// ---------------- fused kernels ----------------

__global__ __launch_bounds__(256) void k_gemm_hist(const float* X, const float* W,
                                                   __half* Y, const int* rows,
                                                   int* gcnt) {
    int b = blockIdx.x;
    if (b < GEMMB) gemm_body(b, X, W, Y);
    else hist_body(b - GEMMB, rows, gcnt);
}

__global__ __launch_bounds__(256) void k_place_gemm_hist(
        const int* rows1, const int* cols1, const float* vals1,
        int* gCursor1, u64* bkt1, float* deg1,
        const float* X2, const float* W2, __half* Y2,
        const int* rows2, int* gcnt2) {
    int b = blockIdx.x;
    if (b < NPB) place_body(b, rows1, cols1, vals1, gCursor1, bkt1, deg1);
    else if (b < NPB + GEMMB) gemm_body(b - NPB, X2, W2, Y2);
    else hist_body(b - NPB - GEMMB, rows2, gcnt2);
}

// place2 (atomic shadow) || fine1 || v1 (streaming rides free)
__global__ __launch_bounds__(256) void k_place_fine_v(
        const int* rows2, const int* cols2, const float* vals2,
        int* gCursor2, u64* bkt2, float* deg2,
        const int* bktBase1, const u64* bkt1, u64* srt1, int* off1,
        const float* X1, const float* deg1, float* v1) {
    int b = blockIdx.x;
    if (b < NPB) place_body(b, rows2, cols2, vals2, gCursor2, bkt2, deg2);
    else if (b < 2 * NPB) fine_body(b - NPB, bktBase1, bkt1, srt1, off1);
    else v_body(b - 2 * NPB, X1, deg1, v1);
}

__global__ __launch_bounds__(256) void k_fine_v(
        const int* bktBase2, const u64* bkt2, u64* srt2, int* off2,
        const float* X2, const float* deg2, float* v2) {
    int b = blockIdx.x;
    if (b < NPB) fine_body(b, bktBase2, bkt2, srt2, off2);
    else v_body(b - NPB, X2, deg2, v2);
}

// cs1 = v1 @ W1 ; cs2 = v2 @ W2   (exact colsum, one block)
__global__ __launch_bounds__(256) void k_cs(const float* __restrict__ v1,
                                            const float* __restrict__ W1,
                                            const float* __restrict__ v2,
                                            const float* __restrict__ W2,
                                            float* __restrict__ cs) {
    int t = threadIdx.x;
    if (t < 128) {
        float s = 0.f;
        for (int k = 0; k < 128; ++k) s += v1[k] * W1[k * 128 + t];
        cs[t] = s;
    } else {
        int c = t - 128;
        float s = 0.f;
        for (int k = 0; k < 128; ++k) s += v2[k] * W2[k * 128 + c];
        cs[128 + c] = s;
    }
}

// both spmms + reweight + final fused: h1 and h2 never touch memory
__global__ __launch_bounds__(256) void k_dual_final(
        const int* __restrict__ off1, const u64* __restrict__ srt1,
        const __half* __restrict__ xmh1,
        const int* __restrict__ off2, const u64* __restrict__ srt2,
        const __half* __restrict__ xmh2,
        float* __restrict__ out, const float* __restrict__ cs) {
    int wid = threadIdx.x >> 6;
    int lane = threadIdx.x & 63;
    int m = blockIdx.x * 4 + wid;
    int c = lane * 2;
    float2 a = spmm_row(m, off1, srt1, xmh1, c);
    float2 b = spmm_row(m, off2, srt2, xmh2, c);
    float w1a = fmaxf(sigmoidf_(cs[c]), 0.f);
    float w1b = fmaxf(sigmoidf_(cs[c + 1]), 0.f);
    float w2a = fmaxf(sigmoidf_(cs[128 + c]), 0.f);
    float w2b = fmaxf(sigmoidf_(cs[129 + c]), 0.f);
    float d1 = w1a * a.x + w1b * a.y;
    float d2 = w2a * b.x + w2b * b.y;
#pragma unroll
    for (int o = 32; o; o >>= 1) {
        d1 += __shfl_xor(d1, o);
        d2 += __shfl_xor(d2, o);
    }
    float s1 = sigmoidf_(d1);
    float s2 = sigmoidf_(d2);
    float2 r;
    r.x = sigmoidf_(0.5f * (s1 * a.x + s2 * b.x));
    r.y = sigmoidf_(0.5f * (s1 * a.y + s2 * b.y));
    *(float2*)&out[(long)m * C + c] = r;
}

// scan of 391 bucket counts -> bktBase, gCursor, off[NM]
__global__ __launch_bounds__(512) void scan_bkt(const int* __restrict__ gBktCnt,
                                                int* __restrict__ bktBase,
                                                int* __restrict__ gCursor,
                                                int* __restrict__ off) {
    __shared__ int wt[8];
    __shared__ int wb[8];
    int t = threadIdx.x;
    int lane = t & 63;
    int wid = t >> 6;
    int v = (t < NBKT) ? gBktCnt[t] : 0;
    int incl = v;
#pragma unroll
    for (int d = 1; d < 64; d <<= 1) {
        int n = __shfl_up(incl, d);
        if (lane >= d) incl += n;
    }
    if (lane == 63) wt[wid] = incl;
    __syncthreads();
    if (t == 0) {
        int r = 0;
#pragma unroll
        for (int i = 0; i < 8; ++i) { wb[i] = r; r += wt[i]; }
    }
    __syncthreads();
    int excl = wb[wid] + incl - v;
    if (t < NBKT) {
        bktBase[t] = excl;
        gCursor[t] = excl;
    }
    if (t == 0) {
        bktBase[NBKT] = NNZE;
        off[NM] = NNZE;
    }
}

extern "C" void kernel_launch(void* const* d_in, const int* in_sizes, int n_in,
                              void* d_out, int out_size, void* d_ws, size_t ws_size,
                              hipStream_t stream) {
    const float* x1 = (const float*)d_in[0];
    const float* x2 = (const float*)d_in[1];
    const int*   n1r = (const int*)d_in[2];
    const int*   n1c = (const int*)d_in[3];
    const float* n1v = (const float*)d_in[4];
    const int*   n2r = (const int*)d_in[5];
    const int*   n2c = (const int*)d_in[6];
    const float* n2v = (const float*)d_in[7];
    const float* W1 = (const float*)d_in[8];
    const float* W2 = (const float*)d_in[9];

    float* outp = (float*)d_out;                     // NM*C fp32 final output
    char* ws = (char*)d_ws;
    size_t o = 0;
    __half* xmh1 = (__half*)(ws + o); o += (size_t)NM * C * sizeof(__half);  // 25.6MB
    __half* xmh2 = (__half*)(ws + o); o += (size_t)NM * C * sizeof(__half);  // 25.6MB
    u64* bkt1 = (u64*)(ws + o);  o += (size_t)NNZE * sizeof(u64);            // 12.8MB
    u64* srt1 = (u64*)(ws + o);  o += (size_t)NNZE * sizeof(u64);            // 12.8MB
    u64* bkt2 = (u64*)(ws + o);  o += (size_t)NNZE * sizeof(u64);            // 12.8MB
    u64* srt2 = (u64*)(ws + o);  o += (size_t)NNZE * sizeof(u64);            // 12.8MB
    // zeroed region (one memset): deg1 deg2 gcnt1 gcnt2 v1 v2
    char* zbase = ws + o;
    float* deg1 = (float*)(ws + o);  o += (size_t)NM * sizeof(float);
    float* deg2 = (float*)(ws + o);  o += (size_t)NM * sizeof(float);
    int* gcnt1  = (int*)(ws + o);    o += (size_t)NBKT * sizeof(int);
    int* gcnt2  = (int*)(ws + o);    o += (size_t)NBKT * sizeof(int);
    float* v1   = (float*)(ws + o);  o += 128 * sizeof(float);
    float* v2   = (float*)(ws + o);  o += 128 * sizeof(float);
    size_t zsize = (size_t)((ws + o) - zbase);
    int* bktBase1 = (int*)(ws + o);  o += (size_t)(NBKT + 1) * sizeof(int);
    int* bktBase2 = (int*)(ws + o);  o += (size_t)(NBKT + 1) * sizeof(int);
    int* gCursor1 = (int*)(ws + o);  o += (size_t)NBKT * sizeof(int);
    int* gCursor2 = (int*)(ws + o);  o += (size_t)NBKT * sizeof(int);
    int* off1 = (int*)(ws + o);      o += (size_t)(NM + 1) * sizeof(int);
    int* off2 = (int*)(ws + o);      o += (size_t)(NM + 1) * sizeof(int);
    float* cs = (float*)(ws + o);    o += 256 * sizeof(float);

    hipMemsetAsync(zbase, 0, zsize, stream);

    // K1: gemm1 || hist1
    k_gemm_hist<<<GEMMB + NPB, 256, 0, stream>>>(x1, W1, xmh1, n1r, gcnt1);
    // K2: scan1
    scan_bkt<<<1, 512, 0, stream>>>(gcnt1, bktBase1, gCursor1, off1);
    // K3: place1 || gemm2 || hist2   (gemm+hist ride in place1's atomic shadow)
    k_place_gemm_hist<<<NPB + GEMMB + NPB, 256, 0, stream>>>(
        n1r, n1c, n1v, gCursor1, bkt1, deg1, x2, W2, xmh2, n2r, gcnt2);
    // K4: scan2
    scan_bkt<<<1, 512, 0, stream>>>(gcnt2, bktBase2, gCursor2, off2);
    // K5: place2 || fine1 || v1      (fine+v ride in place2's atomic shadow)
    k_place_fine_v<<<2 * NPB + VB, 256, 0, stream>>>(
        n2r, n2c, n2v, gCursor2, bkt2, deg2,
        bktBase1, bkt1, srt1, off1, x1, deg1, v1);
    // K6: fine2 || v2
    k_fine_v<<<NPB + VB, 256, 0, stream>>>(
        bktBase2, bkt2, srt2, off2, x2, deg2, v2);
    // K7: cs = v @ W (both convs)
    k_cs<<<1, 256, 0, stream>>>(v1, W1, v2, W2, cs);
    // K8: spmm1 + spmm2 + reweight + final (h1, h2 stay in registers)
    k_dual_final<<<SPMMB, 256, 0, stream>>>(
        off1, srt1, xmh1, off2, srt2, xmh2, outp, cs);
}

// Round 10
// 669.621 us; speedup vs baseline: 1.1999x; 1.1999x over previous
//
#include <hip/hip_runtime.h>
#include <hip/hip_fp16.h>

#define NM 100000
#define NNZE 1600000
#define C 128
#define NBKT 391          // coarse buckets (256 rows each)
#define NPB 391           // blocks of 4096 entries
#define GEMMB 512
#define VB 128
#define SPMMB (NM / 4)

typedef unsigned long long u64;
typedef __attribute__((ext_vector_type(8))) short bf16x8;
typedef __attribute__((ext_vector_type(4))) float f32x4;

__device__ __forceinline__ float sigmoidf_(float x) {
    return 1.0f / (1.0f + __expf(-x));
}
__device__ __forceinline__ short f2bf(float f) {          // fp32 -> bf16 RNE
    unsigned u = __float_as_uint(f);
    return (short)((u + 0x7FFFu + ((u >> 16) & 1u)) >> 16);
}
__device__ __forceinline__ float bf2f(short s) {
    return __uint_as_float(((unsigned)(unsigned short)s) << 16);
}

// ---------------- role bodies ----------------

// Y(fp16) = X @ W via split-bf16 MFMA (xh*Wh + xh*Wl + xl*Wh)
__device__ void gemm_body(int gb, const float* __restrict__ X,
                          const float* __restrict__ W, __half* __restrict__ Y) {
    __shared__ short Whi[16384];   // 32 KB
    __shared__ short Wlo[16384];   // 32 KB
    int t = threadIdx.x;
    for (int e = t; e < 16384; e += 256) {
        int k = e >> 7, c = e & 127;
        float w = W[e];
        short hi = f2bf(w);
        short lo = f2bf(w - bf2f(hi));
        int kt = k >> 5, kin = k & 31, ct = c >> 4, cin = c & 15;
        int lane = ((kin >> 3) << 4) | cin;
        int idx = (((kt << 3) | ct) << 9) + (lane << 3) + (kin & 7);
        Whi[idx] = hi;
        Wlo[idx] = lo;
    }
    __syncthreads();
    int lane = t & 63;
    int wv = t >> 6;
    int gw = gb * 4 + wv;
    const int wstride = GEMMB * 4;
    int r_lane = lane & 15;
    int kg = lane >> 4;
    const int NT = NM / 16;
    for (int tile = gw; tile < NT; tile += wstride) {
        int row = tile * 16 + r_lane;
        bf16x8 ahi[4], alo[4];
#pragma unroll
        for (int kt = 0; kt < 4; ++kt) {
            const float4* xp = (const float4*)&X[(long)row * C + kt * 32 + kg * 8];
            float4 v0 = xp[0];
            float4 v1 = xp[1];
            float vv[8] = {v0.x, v0.y, v0.z, v0.w, v1.x, v1.y, v1.z, v1.w};
#pragma unroll
            for (int q = 0; q < 8; ++q) {
                short h = f2bf(vv[q]);
                ahi[kt][q] = h;
                alo[kt][q] = f2bf(vv[q] - bf2f(h));
            }
        }
        int rbase = tile * 16 + kg * 4;
#pragma unroll
        for (int ct = 0; ct < 8; ++ct) {
            f32x4 acc = {0.f, 0.f, 0.f, 0.f};
#pragma unroll
            for (int kt = 0; kt < 4; ++kt) {
                int bidx = (((kt << 3) | ct) << 9) + (lane << 3);
                bf16x8 bhi = *(bf16x8*)&Whi[bidx];
                bf16x8 blo = *(bf16x8*)&Wlo[bidx];
                acc = __builtin_amdgcn_mfma_f32_16x16x32_bf16(ahi[kt], bhi, acc, 0, 0, 0);
                acc = __builtin_amdgcn_mfma_f32_16x16x32_bf16(ahi[kt], blo, acc, 0, 0, 0);
                acc = __builtin_amdgcn_mfma_f32_16x16x32_bf16(alo[kt], bhi, acc, 0, 0, 0);
            }
            int ccol = ct * 16 + r_lane;
#pragma unroll
            for (int r = 0; r < 4; ++r)
                Y[(long)(rbase + r) * C + ccol] = __float2half(acc[r]);
        }
    }
}

// rows-only coarse bucket histogram (LDS-aggregated)
__device__ void hist_body(int hb, const int* __restrict__ rows,
                          int* __restrict__ gcnt) {
    __shared__ int hcnt[NBKT];
    int t = threadIdx.x;
    for (int j = t; j < NBKT; j += 256) hcnt[j] = 0;
    __syncthreads();
    long base = (long)hb * 4096;
#pragma unroll
    for (int i = 0; i < 16; ++i) {
        long e = base + i * 256 + t;
        if (e < NNZE) atomicAdd(&hcnt[rows[e] >> 8], 1);
    }
    __syncthreads();
    for (int j = t; j < NBKT; j += 256)
        if (hcnt[j]) atomicAdd(&gcnt[j], hcnt[j]);
}

// scatter into coarse buckets (1 global atomic per block-bucket run) + deg scatter
__device__ void place_body(int pb, const int* __restrict__ rows,
                           const int* __restrict__ cols,
                           const float* __restrict__ vals,
                           int* __restrict__ gCursor, u64* __restrict__ bkt,
                           float* __restrict__ deg) {
    __shared__ int lcnt[NBKT];
    __shared__ int lbase[NBKT];
    int t = threadIdx.x;
    for (int j = t; j < NBKT; j += 256) lcnt[j] = 0;
    __syncthreads();
    long base = (long)pb * 4096;
    int myrow[16];
#pragma unroll
    for (int i = 0; i < 16; ++i) {
        long e = base + i * 256 + t;
        myrow[i] = (e < NNZE) ? rows[e] : -1;
        if (myrow[i] >= 0) atomicAdd(&lcnt[myrow[i] >> 8], 1);
    }
    __syncthreads();
    for (int j = t; j < NBKT; j += 256) {
        int cc = lcnt[j];
        lbase[j] = cc ? atomicAdd(&gCursor[j], cc) : 0;
    }
    __syncthreads();
    for (int j = t; j < NBKT; j += 256) lcnt[j] = 0;
    __syncthreads();
#pragma unroll
    for (int i = 0; i < 16; ++i) {
        long e = base + i * 256 + t;
        if (myrow[i] >= 0) {
            int col = cols[e];
            float v = vals[e];
            unsafeAtomicAdd(&deg[col], v);
            int b = myrow[i] >> 8;
            int p = lbase[b] + atomicAdd(&lcnt[b], 1);
            unsigned meta = ((unsigned)(myrow[i] & 255) << 17) | (unsigned)col;
            bkt[p] = (u64)meta | ((u64)__float_as_uint(v) << 32);
        }
    }
}

// one block per bucket: LDS row-count + block scan -> off[] (plain stores),
// then scatter (col,val) into final CSR order
__device__ void fine_body(int fb, const int* __restrict__ bktBase,
                          const u64* __restrict__ bkt, u64* __restrict__ srt,
                          int* __restrict__ off) {
    __shared__ int fcnt[256];
    __shared__ int fexcl[256];
    __shared__ int fwt[4];
    __shared__ int fwb[4];
    int t = threadIdx.x;
    int base = bktBase[fb];
    int n = bktBase[fb + 1] - base;
    fcnt[t] = 0;
    __syncthreads();
    for (int i = t; i < n; i += 256) {
        unsigned meta = (unsigned)(bkt[base + i] & 0xffffffffu);
        atomicAdd(&fcnt[meta >> 17], 1);
    }
    __syncthreads();
    int lane = t & 63;
    int wid = t >> 6;
    int v = fcnt[t];
    int incl = v;
#pragma unroll
    for (int d = 1; d < 64; d <<= 1) {
        int nn = __shfl_up(incl, d);
        if (lane >= d) incl += nn;
    }
    if (lane == 63) fwt[wid] = incl;
    __syncthreads();
    if (t == 0) {
        int r = 0;
#pragma unroll
        for (int i = 0; i < 4; ++i) { fwb[i] = r; r += fwt[i]; }
    }
    __syncthreads();
    int ex = fwb[wid] + incl - v;
    fexcl[t] = ex;
    int row = fb * 256 + t;
    if (row < NM) off[row] = base + ex;
    fcnt[t] = 0;             // reuse as cursor
    __syncthreads();
    for (int i = t; i < n; i += 256) {
        u64 rec = bkt[base + i];
        unsigned meta = (unsigned)(rec & 0xffffffffu);
        int lr = (int)(meta >> 17);
        unsigned col = meta & 0x1ffffu;
        int p = fexcl[lr] + atomicAdd(&fcnt[lr], 1);
        srt[base + p] = (u64)col | (rec & 0xffffffff00000000ull);
    }
}

// v[k] = sum_m deg[m] * X[m][k]  (exact fp32)
__device__ void v_body(int vb, const float* __restrict__ X,
                       const float* __restrict__ deg, float* __restrict__ v) {
    __shared__ float vsh[256];
    int t = threadIdx.x;
    int k = t & 127;
    int half = t >> 7;
    int m0 = vb * 782;
    int m1 = min(m0 + 782, NM);
    float acc = 0.f;
    for (int m = m0 + half; m < m1; m += 2) acc += deg[m] * X[(long)m * C + k];
    vsh[t] = acc;
    __syncthreads();
    if (t < 128) atomicAdd(&v[k], vsh[t] + vsh[t + 128]);
}

// gather-accumulate one CSR row's channel pair (fp16 xm, fp32 acc, unroll-8)
__device__ float2 spmm_row(int m, const int* __restrict__ off,
                           const u64* __restrict__ srt,
                           const __half* __restrict__ xmh, int c) {
    int s = off[m], e = off[m + 1];
    float2 acc[8];
#pragma unroll
    for (int j = 0; j < 8; ++j) acc[j] = make_float2(0.f, 0.f);
    int i = s;
    for (; i + 7 < e; i += 8) {
        u64 p[8];
#pragma unroll
        for (int j = 0; j < 8; ++j) p[j] = srt[i + j];
        float2 xf[8];
#pragma unroll
        for (int j = 0; j < 8; ++j) {
            int cj = (int)(p[j] & 0xffffffffu);
            __half2 hx = *(const __half2*)&xmh[(long)cj * C + c];
            xf[j] = __half22float2(hx);
        }
#pragma unroll
        for (int j = 0; j < 8; ++j) {
            float v = __uint_as_float((unsigned)(p[j] >> 32));
            acc[j].x += v * xf[j].x;
            acc[j].y += v * xf[j].y;
        }
    }
    for (; i < e; ++i) {
        u64 p0 = srt[i];
        int c0 = (int)(p0 & 0xffffffffu);
        float v0 = __uint_as_float((unsigned)(p0 >> 32));
        __half2 hx = *(const __half2*)&xmh[(long)c0 * C + c];
        float2 xf = __half22float2(hx);
        acc[0].x += v0 * xf.x;
        acc[0].y += v0 * xf.y;
    }
#pragma unroll
    for (int j = 1; j < 8; ++j) {
        acc[0].x += acc[j].x;
        acc[0].y += acc[j].y;
    }
    return acc[0];
}

// ---------------- fused kernels (proven combos only) ----------------

__global__ __launch_bounds__(256) void k_gemm_hist(const float* X, const float* W,
                                                   __half* Y, const int* rows,
                                                   int* gcnt) {
    int b = blockIdx.x;
    if (b < GEMMB) gemm_body(b, X, W, Y);
    else hist_body(b - GEMMB, rows, gcnt);
}

__global__ __launch_bounds__(256) void k_place_gemm_hist(
        const int* rows1, const int* cols1, const float* vals1,
        int* gCursor1, u64* bkt1, float* deg1,
        const float* X2, const float* W2, __half* Y2,
        const int* rows2, int* gcnt2) {
    int b = blockIdx.x;
    if (b < NPB) place_body(b, rows1, cols1, vals1, gCursor1, bkt1, deg1);
    else if (b < NPB + GEMMB) gemm_body(b - NPB, X2, W2, Y2);
    else hist_body(b - NPB - GEMMB, rows2, gcnt2);
}

// place2 (atomic shadow) || fine1  (round-8 proven pair)
__global__ __launch_bounds__(256) void k_place_fine(
        const int* rows2, const int* cols2, const float* vals2,
        int* gCursor2, u64* bkt2, float* deg2,
        const int* bktBase1, const u64* bkt1, u64* srt1, int* off1) {
    int b = blockIdx.x;
    if (b < NPB) place_body(b, rows2, cols2, vals2, gCursor2, bkt2, deg2);
    else fine_body(b - NPB, bktBase1, bkt1, srt1, off1);
}

// fine2 || v1 || v2  (all read-mostly, light writes)
__global__ __launch_bounds__(256) void k_fine_vv(
        const int* bktBase2, const u64* bkt2, u64* srt2, int* off2,
        const float* X1, const float* deg1, float* v1,
        const float* X2, const float* deg2, float* v2) {
    int b = blockIdx.x;
    if (b < NPB) fine_body(b, bktBase2, bkt2, srt2, off2);
    else if (b < NPB + VB) v_body(b - NPB, X1, deg1, v1);
    else v_body(b - NPB - VB, X2, deg2, v2);
}

// cs1 = v1 @ W1 ; cs2 = v2 @ W2   (exact colsum, one block)
__global__ __launch_bounds__(256) void k_cs(const float* __restrict__ v1,
                                            const float* __restrict__ W1,
                                            const float* __restrict__ v2,
                                            const float* __restrict__ W2,
                                            float* __restrict__ cs) {
    int t = threadIdx.x;
    if (t < 128) {
        float s = 0.f;
        for (int k = 0; k < 128; ++k) s += v1[k] * W1[k * 128 + t];
        cs[t] = s;
    } else {
        int c = t - 128;
        float s = 0.f;
        for (int k = 0; k < 128; ++k) s += v2[k] * W2[k * 128 + c];
        cs[128 + c] = s;
    }
}

// spmm1 standalone: 25.6MB working set keeps L2 hit rate high
__global__ __launch_bounds__(256) void k_spmm(
        const int* __restrict__ off1, const u64* __restrict__ srt1,
        const __half* __restrict__ xmh1, float* __restrict__ h1) {
    int wid = threadIdx.x >> 6;
    int lane = threadIdx.x & 63;
    int m = blockIdx.x * 4 + wid;
    int c = lane * 2;
    float2 r = spmm_row(m, off1, srt1, xmh1, c);
    *(float2*)&h1[(long)m * C + c] = r;
}

// spmm2 fused with reweight+final: h2 never touches memory, h1 updated in place
__global__ __launch_bounds__(256) void k_spmm_final(
        const int* __restrict__ off2, const u64* __restrict__ srt2,
        const __half* __restrict__ xmh2, float* h1io,
        const float* __restrict__ cs) {
    int wid = threadIdx.x >> 6;
    int lane = threadIdx.x & 63;
    int m = blockIdx.x * 4 + wid;
    int c = lane * 2;
    float2 h2 = spmm_row(m, off2, srt2, xmh2, c);
    float2 a = *(const float2*)&h1io[(long)m * C + c];
    float w1a = fmaxf(sigmoidf_(cs[c]), 0.f);
    float w1b = fmaxf(sigmoidf_(cs[c + 1]), 0.f);
    float w2a = fmaxf(sigmoidf_(cs[128 + c]), 0.f);
    float w2b = fmaxf(sigmoidf_(cs[129 + c]), 0.f);
    float d1 = w1a * a.x + w1b * a.y;
    float d2 = w2a * h2.x + w2b * h2.y;
#pragma unroll
    for (int o = 32; o; o >>= 1) {
        d1 += __shfl_xor(d1, o);
        d2 += __shfl_xor(d2, o);
    }
    float s1 = sigmoidf_(d1);
    float s2 = sigmoidf_(d2);
    float2 out;
    out.x = sigmoidf_(0.5f * (s1 * a.x + s2 * h2.x));
    out.y = sigmoidf_(0.5f * (s1 * a.y + s2 * h2.y));
    *(float2*)&h1io[(long)m * C + c] = out;
}

// scan of 391 bucket counts -> bktBase, gCursor, off[NM]
__global__ __launch_bounds__(512) void scan_bkt(const int* __restrict__ gBktCnt,
                                                int* __restrict__ bktBase,
                                                int* __restrict__ gCursor,
                                                int* __restrict__ off) {
    __shared__ int wt[8];
    __shared__ int wb[8];
    int t = threadIdx.x;
    int lane = t & 63;
    int wid = t >> 6;
    int v = (t < NBKT) ? gBktCnt[t] : 0;
    int incl = v;
#pragma unroll
    for (int d = 1; d < 64; d <<= 1) {
        int n = __shfl_up(incl, d);
        if (lane >= d) incl += n;
    }
    if (lane == 63) wt[wid] = incl;
    __syncthreads();
    if (t == 0) {
        int r = 0;
#pragma unroll
        for (int i = 0; i < 8; ++i) { wb[i] = r; r += wt[i]; }
    }
    __syncthreads();
    int excl = wb[wid] + incl - v;
    if (t < NBKT) {
        bktBase[t] = excl;
        gCursor[t] = excl;
    }
    if (t == 0) {
        bktBase[NBKT] = NNZE;
        off[NM] = NNZE;
    }
}

extern "C" void kernel_launch(void* const* d_in, const int* in_sizes, int n_in,
                              void* d_out, int out_size, void* d_ws, size_t ws_size,
                              hipStream_t stream) {
    const float* x1 = (const float*)d_in[0];
    const float* x2 = (const float*)d_in[1];
    const int*   n1r = (const int*)d_in[2];
    const int*   n1c = (const int*)d_in[3];
    const float* n1v = (const float*)d_in[4];
    const int*   n2r = (const int*)d_in[5];
    const int*   n2c = (const int*)d_in[6];
    const float* n2v = (const float*)d_in[7];
    const float* W1 = (const float*)d_in[8];
    const float* W2 = (const float*)d_in[9];

    float* h1 = (float*)d_out;                       // h1 buffer, then final out
    char* ws = (char*)d_ws;
    size_t o = 0;
    __half* xmh1 = (__half*)(ws + o); o += (size_t)NM * C * sizeof(__half);  // 25.6MB
    __half* xmh2 = (__half*)(ws + o); o += (size_t)NM * C * sizeof(__half);  // 25.6MB
    u64* bkt1 = (u64*)(ws + o);  o += (size_t)NNZE * sizeof(u64);            // 12.8MB
    u64* srt1 = (u64*)(ws + o);  o += (size_t)NNZE * sizeof(u64);            // 12.8MB
    u64* bkt2 = (u64*)(ws + o);  o += (size_t)NNZE * sizeof(u64);            // 12.8MB
    u64* srt2 = (u64*)(ws + o);  o += (size_t)NNZE * sizeof(u64);            // 12.8MB
    // zeroed region (one memset): deg1 deg2 gcnt1 gcnt2 v1 v2
    char* zbase = ws + o;
    float* deg1 = (float*)(ws + o);  o += (size_t)NM * sizeof(float);
    float* deg2 = (float*)(ws + o);  o += (size_t)NM * sizeof(float);
    int* gcnt1  = (int*)(ws + o);    o += (size_t)NBKT * sizeof(int);
    int* gcnt2  = (int*)(ws + o);    o += (size_t)NBKT * sizeof(int);
    float* v1   = (float*)(ws + o);  o += 128 * sizeof(float);
    float* v2   = (float*)(ws + o);  o += 128 * sizeof(float);
    size_t zsize = (size_t)((ws + o) - zbase);
    int* bktBase1 = (int*)(ws + o);  o += (size_t)(NBKT + 1) * sizeof(int);
    int* bktBase2 = (int*)(ws + o);  o += (size_t)(NBKT + 1) * sizeof(int);
    int* gCursor1 = (int*)(ws + o);  o += (size_t)NBKT * sizeof(int);
    int* gCursor2 = (int*)(ws + o);  o += (size_t)NBKT * sizeof(int);
    int* off1 = (int*)(ws + o);      o += (size_t)(NM + 1) * sizeof(int);
    int* off2 = (int*)(ws + o);      o += (size_t)(NM + 1) * sizeof(int);
    float* cs = (float*)(ws + o);    o += 256 * sizeof(float);

    hipMemsetAsync(zbase, 0, zsize, stream);

    // K1: gemm1 || hist1
    k_gemm_hist<<<GEMMB + NPB, 256, 0, stream>>>(x1, W1, xmh1, n1r, gcnt1);
    // K2: scan1
    scan_bkt<<<1, 512, 0, stream>>>(gcnt1, bktBase1, gCursor1, off1);
    // K3: place1 || gemm2 || hist2
    k_place_gemm_hist<<<NPB + GEMMB + NPB, 256, 0, stream>>>(
        n1r, n1c, n1v, gCursor1, bkt1, deg1, x2, W2, xmh2, n2r, gcnt2);
    // K4: scan2
    scan_bkt<<<1, 512, 0, stream>>>(gcnt2, bktBase2, gCursor2, off2);
    // K5: place2 || fine1
    k_place_fine<<<2 * NPB, 256, 0, stream>>>(
        n2r, n2c, n2v, gCursor2, bkt2, deg2, bktBase1, bkt1, srt1, off1);
    // K6: fine2 || v1 || v2
    k_fine_vv<<<NPB + 2 * VB, 256, 0, stream>>>(
        bktBase2, bkt2, srt2, off2, x1, deg1, v1, x2, deg2, v2);
    // K7: cs = v @ W (both convs)
    k_cs<<<1, 256, 0, stream>>>(v1, W1, v2, W2, cs);
    // K8: spmm1 -> h1 (25.6MB working set, L2-friendly)
    k_spmm<<<SPMMB, 256, 0, stream>>>(off1, srt1, xmh1, h1);
    // K9: spmm2 + reweight + final (in place on h1)
    k_spmm_final<<<SPMMB, 256, 0, stream>>>(off2, srt2, xmh2, h1, cs);
}

// Round 11
// 606.044 us; speedup vs baseline: 1.3258x; 1.1049x over previous
//
#include <hip/hip_runtime.h>
#include <hip/hip_fp16.h>

#define NM 100000
#define NNZE 1600000
#define C 128
#define NBKT 391          // coarse buckets (256 rows each)
#define NPB 391           // blocks of 4096 entries
#define GEMMB 512
#define VB 128
#define SPMMB (NM / 4)

typedef unsigned long long u64;
typedef __attribute__((ext_vector_type(8))) short bf16x8;
typedef __attribute__((ext_vector_type(4))) float f32x4;

__device__ __forceinline__ float sigmoidf_(float x) {
    return 1.0f / (1.0f + __expf(-x));
}
__device__ __forceinline__ short f2bf(float f) {          // fp32 -> bf16 RNE
    unsigned u = __float_as_uint(f);
    return (short)((u + 0x7FFFu + ((u >> 16) & 1u)) >> 16);
}
__device__ __forceinline__ float bf2f(short s) {
    return __uint_as_float(((unsigned)(unsigned short)s) << 16);
}

// ---------------- role bodies (each called from EXACTLY ONE call site
// per kernel so function-scope LDS is not duplicated) ----------------

// Y(fp16) = X @ W via split-bf16 MFMA (xh*Wh + xh*Wl + xl*Wh)
__device__ void gemm_body(int gb, const float* __restrict__ X,
                          const float* __restrict__ W, __half* __restrict__ Y) {
    __shared__ short Whi[16384];   // 32 KB
    __shared__ short Wlo[16384];   // 32 KB
    int t = threadIdx.x;
    for (int e = t; e < 16384; e += 256) {
        int k = e >> 7, c = e & 127;
        float w = W[e];
        short hi = f2bf(w);
        short lo = f2bf(w - bf2f(hi));
        int kt = k >> 5, kin = k & 31, ct = c >> 4, cin = c & 15;
        int lane = ((kin >> 3) << 4) | cin;
        int idx = (((kt << 3) | ct) << 9) + (lane << 3) + (kin & 7);
        Whi[idx] = hi;
        Wlo[idx] = lo;
    }
    __syncthreads();
    int lane = t & 63;
    int wv = t >> 6;
    int gw = gb * 4 + wv;
    const int wstride = GEMMB * 4;
    int r_lane = lane & 15;
    int kg = lane >> 4;
    const int NT = NM / 16;
    for (int tile = gw; tile < NT; tile += wstride) {
        int row = tile * 16 + r_lane;
        bf16x8 ahi[4], alo[4];
#pragma unroll
        for (int kt = 0; kt < 4; ++kt) {
            const float4* xp = (const float4*)&X[(long)row * C + kt * 32 + kg * 8];
            float4 v0 = xp[0];
            float4 v1 = xp[1];
            float vv[8] = {v0.x, v0.y, v0.z, v0.w, v1.x, v1.y, v1.z, v1.w};
#pragma unroll
            for (int q = 0; q < 8; ++q) {
                short h = f2bf(vv[q]);
                ahi[kt][q] = h;
                alo[kt][q] = f2bf(vv[q] - bf2f(h));
            }
        }
        int rbase = tile * 16 + kg * 4;
#pragma unroll
        for (int ct = 0; ct < 8; ++ct) {
            f32x4 acc = {0.f, 0.f, 0.f, 0.f};
#pragma unroll
            for (int kt = 0; kt < 4; ++kt) {
                int bidx = (((kt << 3) | ct) << 9) + (lane << 3);
                bf16x8 bhi = *(bf16x8*)&Whi[bidx];
                bf16x8 blo = *(bf16x8*)&Wlo[bidx];
                acc = __builtin_amdgcn_mfma_f32_16x16x32_bf16(ahi[kt], bhi, acc, 0, 0, 0);
                acc = __builtin_amdgcn_mfma_f32_16x16x32_bf16(ahi[kt], blo, acc, 0, 0, 0);
                acc = __builtin_amdgcn_mfma_f32_16x16x32_bf16(alo[kt], bhi, acc, 0, 0, 0);
            }
            int ccol = ct * 16 + r_lane;
#pragma unroll
            for (int r = 0; r < 4; ++r)
                Y[(long)(rbase + r) * C + ccol] = __float2half(acc[r]);
        }
    }
}

// rows-only coarse bucket histogram (LDS-aggregated)
__device__ void hist_body(int hb, const int* __restrict__ rows,
                          int* __restrict__ gcnt) {
    __shared__ int hcnt[NBKT];
    int t = threadIdx.x;
    for (int j = t; j < NBKT; j += 256) hcnt[j] = 0;
    __syncthreads();
    long base = (long)hb * 4096;
#pragma unroll
    for (int i = 0; i < 16; ++i) {
        long e = base + i * 256 + t;
        if (e < NNZE) atomicAdd(&hcnt[rows[e] >> 8], 1);
    }
    __syncthreads();
    for (int j = t; j < NBKT; j += 256)
        if (hcnt[j]) atomicAdd(&gcnt[j], hcnt[j]);
}

// scatter into coarse buckets (1 global atomic per block-bucket run) + deg scatter
__device__ void place_body(int pb, const int* __restrict__ rows,
                           const int* __restrict__ cols,
                           const float* __restrict__ vals,
                           int* __restrict__ gCursor, u64* __restrict__ bkt,
                           float* __restrict__ deg) {
    __shared__ int lcnt[NBKT];
    __shared__ int lbase[NBKT];
    int t = threadIdx.x;
    for (int j = t; j < NBKT; j += 256) lcnt[j] = 0;
    __syncthreads();
    long base = (long)pb * 4096;
    int myrow[16];
#pragma unroll
    for (int i = 0; i < 16; ++i) {
        long e = base + i * 256 + t;
        myrow[i] = (e < NNZE) ? rows[e] : -1;
        if (myrow[i] >= 0) atomicAdd(&lcnt[myrow[i] >> 8], 1);
    }
    __syncthreads();
    for (int j = t; j < NBKT; j += 256) {
        int cc = lcnt[j];
        lbase[j] = cc ? atomicAdd(&gCursor[j], cc) : 0;
    }
    __syncthreads();
    for (int j = t; j < NBKT; j += 256) lcnt[j] = 0;
    __syncthreads();
#pragma unroll
    for (int i = 0; i < 16; ++i) {
        long e = base + i * 256 + t;
        if (myrow[i] >= 0) {
            int col = cols[e];
            float v = vals[e];
            unsafeAtomicAdd(&deg[col], v);
            int b = myrow[i] >> 8;
            int p = lbase[b] + atomicAdd(&lcnt[b], 1);
            unsigned meta = ((unsigned)(myrow[i] & 255) << 17) | (unsigned)col;
            bkt[p] = (u64)meta | ((u64)__float_as_uint(v) << 32);
        }
    }
}

// one block per bucket: LDS row-count + block scan -> off[] (plain stores),
// then scatter (col,val) into final CSR order
__device__ void fine_body(int fb, const int* __restrict__ bktBase,
                          const u64* __restrict__ bkt, u64* __restrict__ srt,
                          int* __restrict__ off) {
    __shared__ int fcnt[256];
    __shared__ int fexcl[256];
    __shared__ int fwt[4];
    __shared__ int fwb[4];
    int t = threadIdx.x;
    int base = bktBase[fb];
    int n = bktBase[fb + 1] - base;
    fcnt[t] = 0;
    __syncthreads();
    for (int i = t; i < n; i += 256) {
        unsigned meta = (unsigned)(bkt[base + i] & 0xffffffffu);
        atomicAdd(&fcnt[meta >> 17], 1);
    }
    __syncthreads();
    int lane = t & 63;
    int wid = t >> 6;
    int v = fcnt[t];
    int incl = v;
#pragma unroll
    for (int d = 1; d < 64; d <<= 1) {
        int nn = __shfl_up(incl, d);
        if (lane >= d) incl += nn;
    }
    if (lane == 63) fwt[wid] = incl;
    __syncthreads();
    if (t == 0) {
        int r = 0;
#pragma unroll
        for (int i = 0; i < 4; ++i) { fwb[i] = r; r += fwt[i]; }
    }
    __syncthreads();
    int ex = fwb[wid] + incl - v;
    fexcl[t] = ex;
    int row = fb * 256 + t;
    if (row < NM) off[row] = base + ex;
    fcnt[t] = 0;             // reuse as cursor
    __syncthreads();
    for (int i = t; i < n; i += 256) {
        u64 rec = bkt[base + i];
        unsigned meta = (unsigned)(rec & 0xffffffffu);
        int lr = (int)(meta >> 17);
        unsigned col = meta & 0x1ffffu;
        int p = fexcl[lr] + atomicAdd(&fcnt[lr], 1);
        srt[base + p] = (u64)col | (rec & 0xffffffff00000000ull);
    }
}

// v[k] = sum_m deg[m] * X[m][k]  (exact fp32)
__device__ void v_body(int vb, const float* __restrict__ X,
                       const float* __restrict__ deg, float* __restrict__ v) {
    __shared__ float vsh[256];
    int t = threadIdx.x;
    int k = t & 127;
    int half = t >> 7;
    int m0 = vb * 782;
    int m1 = min(m0 + 782, NM);
    float acc = 0.f;
    for (int m = m0 + half; m < m1; m += 2) acc += deg[m] * X[(long)m * C + k];
    vsh[t] = acc;
    __syncthreads();
    if (t < 128) atomicAdd(&v[k], vsh[t] + vsh[t + 128]);
}

// gather-accumulate one CSR row's channel pair (fp16 xm, fp32 acc, unroll-8)
__device__ float2 spmm_row(int m, const int* __restrict__ off,
                           const u64* __restrict__ srt,
                           const __half* __restrict__ xmh, int c) {
    int s = off[m], e = off[m + 1];
    float2 acc[8];
#pragma unroll
    for (int j = 0; j < 8; ++j) acc[j] = make_float2(0.f, 0.f);
    int i = s;
    for (; i + 7 < e; i += 8) {
        u64 p[8];
#pragma unroll
        for (int j = 0; j < 8; ++j) p[j] = srt[i + j];
        float2 xf[8];
#pragma unroll
        for (int j = 0; j < 8; ++j) {
            int cj = (int)(p[j] & 0xffffffffu);
            __half2 hx = *(const __half2*)&xmh[(long)cj * C + c];
            xf[j] = __half22float2(hx);
        }
#pragma unroll
        for (int j = 0; j < 8; ++j) {
            float v = __uint_as_float((unsigned)(p[j] >> 32));
            acc[j].x += v * xf[j].x;
            acc[j].y += v * xf[j].y;
        }
    }
    for (; i < e; ++i) {
        u64 p0 = srt[i];
        int c0 = (int)(p0 & 0xffffffffu);
        float v0 = __uint_as_float((unsigned)(p0 >> 32));
        __half2 hx = *(const __half2*)&xmh[(long)c0 * C + c];
        float2 xf = __half22float2(hx);
        acc[0].x += v0 * xf.x;
        acc[0].y += v0 * xf.y;
    }
#pragma unroll
    for (int j = 1; j < 8; ++j) {
        acc[0].x += acc[j].x;
        acc[0].y += acc[j].y;
    }
    return acc[0];
}

// ---------------- kernels ----------------

// both gemms (1024 blocks of real work) + both hists (ride along)
__global__ __launch_bounds__(256) void k_gemm_hist_all(
        const float* x1, const float* W1, __half* xmh1, const int* n1r, int* gcnt1,
        const float* x2, const float* W2, __half* xmh2, const int* n2r, int* gcnt2) {
    int b = blockIdx.x;
    if (b < 2 * GEMMB) {
        bool c2 = b >= GEMMB;
        gemm_body(c2 ? b - GEMMB : b, c2 ? x2 : x1, c2 ? W2 : W1, c2 ? xmh2 : xmh1);
    } else {
        int hb = b - 2 * GEMMB;
        bool c2 = hb >= NPB;
        hist_body(c2 ? hb - NPB : hb, c2 ? n2r : n1r, c2 ? gcnt2 : gcnt1);
    }
}

// scan both convs' bucket counts (2 blocks)
__global__ __launch_bounds__(512) void k_scan_both(
        const int* gcnt1, int* bktBase1, int* gCursor1, int* off1,
        const int* gcnt2, int* bktBase2, int* gCursor2, int* off2) {
    bool c2 = blockIdx.x == 1;
    const int* gBktCnt = c2 ? gcnt2 : gcnt1;
    int* bktBase = c2 ? bktBase2 : bktBase1;
    int* gCursor = c2 ? gCursor2 : gCursor1;
    int* off = c2 ? off2 : off1;
    __shared__ int wt[8];
    __shared__ int wb[8];
    int t = threadIdx.x;
    int lane = t & 63;
    int wid = t >> 6;
    int v = (t < NBKT) ? gBktCnt[t] : 0;
    int incl = v;
#pragma unroll
    for (int d = 1; d < 64; d <<= 1) {
        int n = __shfl_up(incl, d);
        if (lane >= d) incl += n;
    }
    if (lane == 63) wt[wid] = incl;
    __syncthreads();
    if (t == 0) {
        int r = 0;
#pragma unroll
        for (int i = 0; i < 8; ++i) { wb[i] = r; r += wt[i]; }
    }
    __syncthreads();
    int excl = wb[wid] + incl - v;
    if (t < NBKT) {
        bktBase[t] = excl;
        gCursor[t] = excl;
    }
    if (t == 0) {
        bktBase[NBKT] = NNZE;
        off[NM] = NNZE;
    }
}

// both places in one wide kernel (782 blocks, all low-resource -> high occupancy;
// reads/writes of one conv pipeline against the other's atomic stalls)
__global__ __launch_bounds__(256) void k_place_both(
        const int* n1r, const int* n1c, const float* n1v,
        int* gCursor1, u64* bkt1, float* deg1,
        const int* n2r, const int* n2c, const float* n2v,
        int* gCursor2, u64* bkt2, float* deg2) {
    int b = blockIdx.x;
    bool c2 = b >= NPB;
    place_body(c2 ? b - NPB : b,
               c2 ? n2r : n1r, c2 ? n2c : n1c, c2 ? n2v : n1v,
               c2 ? gCursor2 : gCursor1, c2 ? bkt2 : bkt1, c2 ? deg2 : deg1);
}

// both fines + both v reductions (all read-mostly, light writes)
__global__ __launch_bounds__(256) void k_fine_v_both(
        const int* bktBase1, const u64* bkt1, u64* srt1, int* off1,
        const int* bktBase2, const u64* bkt2, u64* srt2, int* off2,
        const float* x1, const float* deg1, float* v1,
        const float* x2, const float* deg2, float* v2) {
    int b = blockIdx.x;
    if (b < 2 * NPB) {
        bool c2 = b >= NPB;
        fine_body(c2 ? b - NPB : b, c2 ? bktBase2 : bktBase1,
                  c2 ? bkt2 : bkt1, c2 ? srt2 : srt1, c2 ? off2 : off1);
    } else {
        int vb = b - 2 * NPB;
        bool c2 = vb >= VB;
        v_body(c2 ? vb - VB : vb, c2 ? x2 : x1, c2 ? deg2 : deg1, c2 ? v2 : v1);
    }
}

// cs1 = v1 @ W1 ; cs2 = v2 @ W2   (exact colsum, one block)
__global__ __launch_bounds__(256) void k_cs(const float* __restrict__ v1,
                                            const float* __restrict__ W1,
                                            const float* __restrict__ v2,
                                            const float* __restrict__ W2,
                                            float* __restrict__ cs) {
    int t = threadIdx.x;
    if (t < 128) {
        float s = 0.f;
        for (int k = 0; k < 128; ++k) s += v1[k] * W1[k * 128 + t];
        cs[t] = s;
    } else {
        int c = t - 128;
        float s = 0.f;
        for (int k = 0; k < 128; ++k) s += v2[k] * W2[k * 128 + c];
        cs[128 + c] = s;
    }
}

// spmm1 standalone: 25.6MB working set keeps L2 hit rate high
__global__ __launch_bounds__(256) void k_spmm(
        const int* __restrict__ off1, const u64* __restrict__ srt1,
        const __half* __restrict__ xmh1, float* __restrict__ h1) {
    int wid = threadIdx.x >> 6;
    int lane = threadIdx.x & 63;
    int m = blockIdx.x * 4 + wid;
    int c = lane * 2;
    float2 r = spmm_row(m, off1, srt1, xmh1, c);
    *(float2*)&h1[(long)m * C + c] = r;
}

// spmm2 fused with reweight+final: h2 never touches memory, h1 updated in place
__global__ __launch_bounds__(256) void k_spmm_final(
        const int* __restrict__ off2, const u64* __restrict__ srt2,
        const __half* __restrict__ xmh2, float* h1io,
        const float* __restrict__ cs) {
    int wid = threadIdx.x >> 6;
    int lane = threadIdx.x & 63;
    int m = blockIdx.x * 4 + wid;
    int c = lane * 2;
    float2 h2 = spmm_row(m, off2, srt2, xmh2, c);
    float2 a = *(const float2*)&h1io[(long)m * C + c];
    float w1a = fmaxf(sigmoidf_(cs[c]), 0.f);
    float w1b = fmaxf(sigmoidf_(cs[c + 1]), 0.f);
    float w2a = fmaxf(sigmoidf_(cs[128 + c]), 0.f);
    float w2b = fmaxf(sigmoidf_(cs[129 + c]), 0.f);
    float d1 = w1a * a.x + w1b * a.y;
    float d2 = w2a * h2.x + w2b * h2.y;
#pragma unroll
    for (int o = 32; o; o >>= 1) {
        d1 += __shfl_xor(d1, o);
        d2 += __shfl_xor(d2, o);
    }
    float s1 = sigmoidf_(d1);
    float s2 = sigmoidf_(d2);
    float2 out;
    out.x = sigmoidf_(0.5f * (s1 * a.x + s2 * h2.x));
    out.y = sigmoidf_(0.5f * (s1 * a.y + s2 * h2.y));
    *(float2*)&h1io[(long)m * C + c] = out;
}

extern "C" void kernel_launch(void* const* d_in, const int* in_sizes, int n_in,
                              void* d_out, int out_size, void* d_ws, size_t ws_size,
                              hipStream_t stream) {
    const float* x1 = (const float*)d_in[0];
    const float* x2 = (const float*)d_in[1];
    const int*   n1r = (const int*)d_in[2];
    const int*   n1c = (const int*)d_in[3];
    const float* n1v = (const float*)d_in[4];
    const int*   n2r = (const int*)d_in[5];
    const int*   n2c = (const int*)d_in[6];
    const float* n2v = (const float*)d_in[7];
    const float* W1 = (const float*)d_in[8];
    const float* W2 = (const float*)d_in[9];

    float* h1 = (float*)d_out;                       // h1 buffer, then final out
    char* ws = (char*)d_ws;
    size_t o = 0;
    __half* xmh1 = (__half*)(ws + o); o += (size_t)NM * C * sizeof(__half);  // 25.6MB
    __half* xmh2 = (__half*)(ws + o); o += (size_t)NM * C * sizeof(__half);  // 25.6MB
    u64* bkt1 = (u64*)(ws + o);  o += (size_t)NNZE * sizeof(u64);            // 12.8MB
    u64* srt1 = (u64*)(ws + o);  o += (size_t)NNZE * sizeof(u64);            // 12.8MB
    u64* bkt2 = (u64*)(ws + o);  o += (size_t)NNZE * sizeof(u64);            // 12.8MB
    u64* srt2 = (u64*)(ws + o);  o += (size_t)NNZE * sizeof(u64);            // 12.8MB
    // zeroed region (one memset): deg1 deg2 gcnt1 gcnt2 v1 v2
    char* zbase = ws + o;
    float* deg1 = (float*)(ws + o);  o += (size_t)NM * sizeof(float);
    float* deg2 = (float*)(ws + o);  o += (size_t)NM * sizeof(float);
    int* gcnt1  = (int*)(ws + o);    o += (size_t)NBKT * sizeof(int);
    int* gcnt2  = (int*)(ws + o);    o += (size_t)NBKT * sizeof(int);
    float* v1   = (float*)(ws + o);  o += 128 * sizeof(float);
    float* v2   = (float*)(ws + o);  o += 128 * sizeof(float);
    size_t zsize = (size_t)((ws + o) - zbase);
    int* bktBase1 = (int*)(ws + o);  o += (size_t)(NBKT + 1) * sizeof(int);
    int* bktBase2 = (int*)(ws + o);  o += (size_t)(NBKT + 1) * sizeof(int);
    int* gCursor1 = (int*)(ws + o);  o += (size_t)NBKT * sizeof(int);
    int* gCursor2 = (int*)(ws + o);  o += (size_t)NBKT * sizeof(int);
    int* off1 = (int*)(ws + o);      o += (size_t)(NM + 1) * sizeof(int);
    int* off2 = (int*)(ws + o);      o += (size_t)(NM + 1) * sizeof(int);
    float* cs = (float*)(ws + o);    o += 256 * sizeof(float);

    hipMemsetAsync(zbase, 0, zsize, stream);

    // K1: gemm1 + gemm2 (1024 blocks) with hist1 + hist2 riding
    k_gemm_hist_all<<<2 * GEMMB + 2 * NPB, 256, 0, stream>>>(
        x1, W1, xmh1, n1r, gcnt1, x2, W2, xmh2, n2r, gcnt2);
    // K2: both scans
    k_scan_both<<<2, 512, 0, stream>>>(gcnt1, bktBase1, gCursor1, off1,
                                       gcnt2, bktBase2, gCursor2, off2);
    // K3: both places wide (atomic-fabric phase, maximum width)
    k_place_both<<<2 * NPB, 256, 0, stream>>>(
        n1r, n1c, n1v, gCursor1, bkt1, deg1,
        n2r, n2c, n2v, gCursor2, bkt2, deg2);
    // K4: both fines + v1 + v2
    k_fine_v_both<<<2 * NPB + 2 * VB, 256, 0, stream>>>(
        bktBase1, bkt1, srt1, off1, bktBase2, bkt2, srt2, off2,
        x1, deg1, v1, x2, deg2, v2);
    // K5: cs = v @ W (both convs, exact)
    k_cs<<<1, 256, 0, stream>>>(v1, W1, v2, W2, cs);
    // K6: spmm1 -> h1 (25.6MB working set, L2-friendly)
    k_spmm<<<SPMMB, 256, 0, stream>>>(off1, srt1, xmh1, h1);
    // K7: spmm2 + reweight + final (in place on h1)
    k_spmm_final<<<SPMMB, 256, 0, stream>>>(off2, srt2, xmh2, h1, cs);
}